// Round 1
// baseline (55.353 us; speedup 1.0000x reference)
//
#include <hip/hip_runtime.h>

constexpr int C  = 21;
constexpr int CC = C * C;   // 441 bins per batch
constexpr int NSUB = 4;     // one sub-histogram per wave (256 threads = 4 waves)

__global__ void zero_out_kernel(float* __restrict__ out, int n) {
    int i = blockIdx.x * blockDim.x + threadIdx.x;
    if (i < n) out[i] = 0.0f;
}

__global__ __launch_bounds__(256)
void conf_hist_kernel(const int* __restrict__ yp,
                      const int* __restrict__ y,
                      float* __restrict__ out,
                      int n_per_batch,        // pixels per batch (multiple of 4)
                      int blocks_per_batch) {
    __shared__ unsigned int hist[NSUB][CC];

    const int tid = threadIdx.x;

    // zero LDS histograms
    for (int i = tid; i < NSUB * CC; i += blockDim.x)
        ((unsigned int*)hist)[i] = 0u;
    __syncthreads();

    const int b   = blockIdx.x / blocks_per_batch;
    const int blk = blockIdx.x % blocks_per_batch;

    const int4* yp4 = (const int4*)(yp + (size_t)b * n_per_batch);
    const int4* y4  = (const int4*)(y  + (size_t)b * n_per_batch);
    const int n4 = n_per_batch >> 2;

    const int wave = tid >> 6;
    unsigned int* h = hist[wave];

    // coalesced grid-stride over int4 groups within this batch
    for (int i = blk * (int)blockDim.x + tid; i < n4;
         i += blocks_per_batch * (int)blockDim.x) {
        int4 a = yp4[i];
        int4 c = y4[i];
        atomicAdd(&h[a.x * C + c.x], 1u);
        atomicAdd(&h[a.y * C + c.y], 1u);
        atomicAdd(&h[a.z * C + c.z], 1u);
        atomicAdd(&h[a.w * C + c.w], 1u);
    }
    __syncthreads();

    // merge sub-histograms, one float atomic per nonzero bin
    float* ob = out + (size_t)b * CC;
    for (int i = tid; i < CC; i += blockDim.x) {
        unsigned int s = hist[0][i] + hist[1][i] + hist[2][i] + hist[3][i];
        if (s) atomicAdd(&ob[i], (float)s);
    }
}

extern "C" void kernel_launch(void* const* d_in, const int* in_sizes, int n_in,
                              void* d_out, int out_size, void* d_ws, size_t ws_size,
                              hipStream_t stream) {
    const int* yp = (const int*)d_in[0];
    const int* y  = (const int*)d_in[1];
    float* out    = (float*)d_out;

    const int total = in_sizes[0];          // B*H*W = 33,554,432
    const int B = out_size / CC;            // 8
    const int n_per_batch = total / B;      // 4,194,304

    // zero the (0xAA-poisoned) output
    zero_out_kernel<<<(out_size + 255) / 256, 256, 0, stream>>>(out, out_size);

    const int blocks_per_batch = 256;       // 2048 blocks total, ~8/CU
    conf_hist_kernel<<<B * blocks_per_batch, 256, 0, stream>>>(
        yp, y, out, n_per_batch, blocks_per_batch);
}